// Round 1
// baseline (84.130 us; speedup 1.0000x reference)
//
#include <hip/hip_runtime.h>

#define GH 32
#define GW 32
#define PITCH 34          // 32 + 2 halo (halo doubles as out-of-bounds INF)
#define NPAD (PITCH * PITCH)
#define INFV 1000000000.0f
#define EPSV 1e-6f

__global__ __launch_bounds__(1024)
void bbastar_kernel(const float* __restrict__ weights,
                    const int* __restrict__ source,
                    const int* __restrict__ target,
                    float* __restrict__ out) {
    __shared__ float d[NPAD];
    __shared__ int flags[16];

    const int b   = blockIdx.x;
    const int tid = threadIdx.x;
    const int r   = tid >> 5;
    const int c   = tid & 31;
    const int addr = (r + 1) * PITCH + (c + 1);

    const int sr = source[2 * b];
    const int sc = source[2 * b + 1];

    // w = weights + EPS, same single f32 add as the reference
    const float w = weights[b * (GH * GW) + tid] + EPSV;

    // zero this batch's output region (harness poisons d_out with 0xAA)
    out[b * (GH * GW) + tid] = 0.0f;

    // init dist: INF everywhere (incl. halo), source = w[source]
    for (int i = tid; i < NPAD; i += 1024) d[i] = INFV;
    __syncthreads();
    const bool is_src = (r == sr) && (c == sc);
    float myd = is_src ? w : INFV;
    if (is_src) d[addr] = w;
    __syncthreads();

    // Relaxation to fixed point. In-place (Gauss-Seidel-ish) updates are
    // safe: every assigned value is a float32 walk-sum from the source, the
    // map is monotone non-increasing, and the certified no-change sweep
    // proves we reached the unique least fixed point — identical floats to
    // the reference's 1024 Jacobi sweeps.
    for (int it = 0; it < 2048; ++it) {
        const float n0 = d[addr - PITCH - 1];
        const float n1 = d[addr - PITCH];
        const float n2 = d[addr - PITCH + 1];
        const float n3 = d[addr - 1];
        const float n4 = d[addr + 1];
        const float n5 = d[addr + PITCH - 1];
        const float n6 = d[addr + PITCH];
        const float n7 = d[addr + PITCH + 1];
        const float nmin = fminf(fminf(fminf(n0, n1), fminf(n2, n3)),
                                 fminf(fminf(n4, n5), fminf(n6, n7)));
        const float nd = w + nmin;          // single add, matches reference
        const bool ch = nd < myd;
        if (ch) { myd = nd; d[addr] = nd; }

        const unsigned long long bal = __ballot(ch);
        if ((tid & 63) == 0) flags[tid >> 6] = (bal != 0ULL) ? 1 : 0;
        __syncthreads();                    // flags + d updates visible
        int any = 0;
        #pragma unroll
        for (int i = 0; i < 16; ++i) any |= flags[i];  // broadcast reads
        if (!any) break;                    // uniform across block
        __syncthreads();                    // protect flags/d for next sweep
    }

    // Greedy backtrack, thread 0 only. Halo cells are exactly INFV, matching
    // the reference's where(valid, dvals, INF). Strict '<' scan in OFFS order
    // replicates jnp.argmin first-min tie-breaking.
    if (tid == 0) {
        const int drr[8] = {-1, -1, -1,  0, 0,  1, 1, 1};
        const int dcc[8] = {-1,  0,  1, -1, 1, -1, 0, 1};
        int pr = target[2 * b];
        int pc = target[2 * b + 1];
        float* ob = out + b * (GH * GW);
        for (int step = 0; step < GH * GW; ++step) {
            ob[pr * GW + pc] = 1.0f;
            if (pr == sr && pc == sc) break;
            float best = INFV;
            int bj = 0;
            #pragma unroll
            for (int j = 0; j < 8; ++j) {
                const float v = d[(pr + drr[j] + 1) * PITCH + (pc + dcc[j] + 1)];
                if (v < best) { best = v; bj = j; }
            }
            pr += drr[bj];
            pc += dcc[bj];
        }
    }
}

extern "C" void kernel_launch(void* const* d_in, const int* in_sizes, int n_in,
                              void* d_out, int out_size, void* d_ws, size_t ws_size,
                              hipStream_t stream) {
    const float* weights = (const float*)d_in[0];
    const int*   source  = (const int*)d_in[1];
    const int*   target  = (const int*)d_in[2];
    float*       out     = (float*)d_out;
    const int B = in_sizes[0] / (GH * GW);
    bbastar_kernel<<<B, 1024, 0, stream>>>(weights, source, target, out);
}

// Round 2
// 79.937 us; speedup vs baseline: 1.0524x; 1.0524x over previous
//
#include <hip/hip_runtime.h>

#define GH 32
#define GW 32
#define PITCH 34          // 32 + 2 halo (halo doubles as out-of-bounds INF)
#define NPAD (PITCH * PITCH)
#define INFV 1000000000.0f
#define EPSV 1e-6f

// 256 threads: thread owns 4 horizontally-adjacent cells (r, 4q .. 4q+3).
// r = tid>>3 (0..31), q = tid&7 (0..7).
__global__ __launch_bounds__(256)
void bbastar_kernel(const float* __restrict__ weights,
                    const int* __restrict__ source,
                    const int* __restrict__ target,
                    float* __restrict__ out) {
    __shared__ float d[NPAD];
    __shared__ int flags[2][4];

    const int b   = blockIdx.x;
    const int tid = threadIdx.x;
    const int r   = tid >> 3;
    const int q   = tid & 7;
    const int c0  = q << 2;
    const int base = (r + 1) * PITCH + (c0 + 1);   // LDS addr of cell (r, c0)

    const int sr = source[2 * b];
    const int sc = source[2 * b + 1];

    // w = weights + EPS (single f32 add, matches reference). float4 load.
    const float4 w4 = ((const float4*)(weights + b * (GH * GW)))[tid];
    float w[4] = { w4.x + EPSV, w4.y + EPSV, w4.z + EPSV, w4.w + EPSV };

    // zero this batch's output region (harness poisons d_out with 0xAA)
    ((float4*)(out + b * (GH * GW)))[tid] = make_float4(0.f, 0.f, 0.f, 0.f);

    // init dist: INF everywhere (incl. halo), then source = w[source]
    for (int i = tid; i < NPAD; i += 256) d[i] = INFV;
    __syncthreads();
    float myd[4];
    #pragma unroll
    for (int k = 0; k < 4; ++k) {
        const bool is_src = (r == sr) && (c0 + k == sc);
        myd[k] = is_src ? w[k] : INFV;
        if (is_src) d[base + k] = w[k];
    }
    __syncthreads();

    // Relaxation to the unique least fixed point. In-place updates and the
    // in-register Gauss-Seidel order are schedule choices only: every value
    // is a float32 walk-sum fl(...fl(w_s+w_a)+w_b...) from the source, the
    // relaxation map is monotone, so the certified no-change sweep proves we
    // reached the same floats as the reference's 1024 Jacobi sweeps.
    for (int it = 0; it < 2048; ++it) {
        // shared neighbor fetches for the quad: rows r-1 / r+1, cols c0-1..c0+4,
        // plus left/right flank on row r. 14 LDS reads cover all 4 cells.
        float t[6], btm[6];
        #pragma unroll
        for (int k = 0; k < 6; ++k) {
            t[k]   = d[base - PITCH - 1 + k];
            btm[k] = d[base + PITCH - 1 + k];
        }
        const float lft = d[base - 1];
        const float rgt = d[base + 4];

        bool ch = false;
        if ((it & 1) == 0) {
            #pragma unroll
            for (int k = 0; k < 4; ++k) {
                const float lnb = (k == 0) ? lft : myd[k - 1];
                const float rnb = (k == 3) ? rgt : myd[k + 1];
                const float nmin = fminf(fminf(fminf(t[k], t[k + 1]), fminf(t[k + 2], btm[k])),
                                         fminf(fminf(btm[k + 1], btm[k + 2]), fminf(lnb, rnb)));
                const float nd = w[k] + nmin;
                if (nd < myd[k]) { myd[k] = nd; d[base + k] = nd; ch = true; }
            }
        } else {
            #pragma unroll
            for (int k = 3; k >= 0; --k) {
                const float lnb = (k == 0) ? lft : myd[k - 1];
                const float rnb = (k == 3) ? rgt : myd[k + 1];
                const float nmin = fminf(fminf(fminf(t[k], t[k + 1]), fminf(t[k + 2], btm[k])),
                                         fminf(fminf(btm[k + 1], btm[k + 2]), fminf(lnb, rnb)));
                const float nd = w[k] + nmin;
                if (nd < myd[k]) { myd[k] = nd; d[base + k] = nd; ch = true; }
            }
        }

        // convergence check: 1 barrier/sweep, double-buffered flags
        const unsigned long long bal = __ballot(ch);
        if ((tid & 63) == 0) flags[it & 1][tid >> 6] = (bal != 0ULL) ? 1 : 0;
        __syncthreads();                 // d updates + this sweep's flags visible
        const int any = flags[it & 1][0] | flags[it & 1][1] |
                        flags[it & 1][2] | flags[it & 1][3];
        if (!any) break;                 // uniform across block
        // next sweep writes flags[(it+1)&1]; reuse of flags[it&1] happens only
        // after the NEXT barrier, by which time every thread has read it.
    }

    // Greedy backtrack, thread 0 only. Halo cells are exactly INFV, matching
    // the reference's where(valid, dvals, INF). Strict '<' scan in OFFS order
    // replicates jnp.argmin first-min tie-breaking.
    if (tid == 0) {
        const int drr[8] = {-1, -1, -1,  0, 0,  1, 1, 1};
        const int dcc[8] = {-1,  0,  1, -1, 1, -1, 0, 1};
        int pr = target[2 * b];
        int pc = target[2 * b + 1];
        float* ob = out + b * (GH * GW);
        for (int step = 0; step < GH * GW; ++step) {
            ob[pr * GW + pc] = 1.0f;
            if (pr == sr && pc == sc) break;
            float best = INFV;
            int bj = 0;
            #pragma unroll
            for (int j = 0; j < 8; ++j) {
                const float v = d[(pr + drr[j] + 1) * PITCH + (pc + dcc[j] + 1)];
                if (v < best) { best = v; bj = j; }
            }
            pr += drr[bj];
            pc += dcc[bj];
        }
    }
}

extern "C" void kernel_launch(void* const* d_in, const int* in_sizes, int n_in,
                              void* d_out, int out_size, void* d_ws, size_t ws_size,
                              hipStream_t stream) {
    const float* weights = (const float*)d_in[0];
    const int*   source  = (const int*)d_in[1];
    const int*   target  = (const int*)d_in[2];
    float*       out     = (float*)d_out;
    const int B = in_sizes[0] / (GH * GW);
    bbastar_kernel<<<B, 256, 0, stream>>>(weights, source, target, out);
}